// Round 3
// baseline (1393.459 us; speedup 1.0000x reference)
//
#include <hip/hip_runtime.h>

// CostVolume1D: out[n,i,h,w] = (1/C) * sum_c f1[n,c,h,w] * f2pad[n,c,h,w+i-4]
// N=4, C=128, H=192, W=640, D=4 -> 9 shifts. Latency-bound until now:
// grid only supplied 15 waves/CU. R3: split the channel reduction across
// 2 waves per block (c in [0,64) / [64,128)) -> 7680 waves = 30/CU, blocks
// = 3840 = exactly 15/CU (balanced). ONE barrier per kernel for the LDS
// combine. Loads are unconditional (clamped offset + 0/1 mask, computed
// once); f2 addressed as block-uniform SGPR base + per-lane byte offset;
// register pipeline prefetch distance 4 (24 outstanding loads/wave).

constexpr int DD = 4;
constexpr int NS = 2 * DD + 1;          // 9
constexpr int N_ = 4, C_ = 128, H_ = 192, W_ = 640;
constexpr int HW = H_ * W_;
constexpr int SEGS  = W_ / 128;         // 5 wave-segments per row
constexpr int TILES = N_ * H_ * SEGS;   // 3840 blocks
constexpr int CH    = C_ / 2;           // 64 channels per wave
constexpr int PF    = 4;                // prefetch stages

__global__ __launch_bounds__(128, 6)
void cost_volume_kernel(const float* __restrict__ f1,
                        const float* __restrict__ f2,
                        float* __restrict__ out)
{
    const int lane = threadIdx.x & 63;
    const int half = threadIdx.x >> 6;      // which C-half this wave owns
    const int tile = blockIdx.x;
    const int seg  = tile % SEGS;
    const int row  = tile / SEGS;           // n*H + h
    const int n    = row / H_;
    const int h    = row - n * H_;
    const int w0   = seg * 128 + lane * 2;  // this lane's w in [0, 640)

    const size_t base = (size_t)n * C_ * HW + (size_t)h * W_;
    const int    c0   = half * CH;

    // block-uniform bases (SGPR); per-lane element offsets (VGPR)
    const float* f2b = f2 + base + (size_t)c0 * HW;
    const float* f1p = f1 + base + (size_t)c0 * HW + w0;

    // five f2 pair-offsets: w0-4+2k, clamped in-bounds, 0/1 mask
    int   voff[5];
    float mk[5];
#pragma unroll
    for (int k = 0; k < 5; ++k) {
        const int off   = w0 - 4 + 2 * k;
        const bool ok   = (off >= 0) && (off <= W_ - 2);
        voff[k] = ok ? off : 0;
        mk[k]   = ok ? 1.f : 0.f;
    }

    float2 A[PF];
    float2 B[PF][5];

    auto load_stage = [&](int s, int c) {
        A[s] = *(const float2*)(f1p + (size_t)c * HW);
        const float* f2c = f2b + (size_t)c * HW;
#pragma unroll
        for (int k = 0; k < 5; ++k)
            B[s][k] = *(const float2*)(f2c + voff[k]);
    };

    float acc0[NS], acc1[NS];
#pragma unroll
    for (int i = 0; i < NS; ++i) { acc0[i] = 0.f; acc1[i] = 0.f; }

#pragma unroll
    for (int s = 0; s < PF; ++s) load_stage(s, s);

#pragma unroll 4
    for (int c = 0; c < CH; ++c) {
        const int s = c & (PF - 1);
        const float2 a = A[s];
        float v[10];
#pragma unroll
        for (int k = 0; k < 5; ++k) {
            v[2 * k]     = B[s][k].x * mk[k];
            v[2 * k + 1] = B[s][k].y * mk[k];
        }
#pragma unroll
        for (int i = 0; i < NS; ++i) {
            acc0[i] = fmaf(a.x, v[i],     acc0[i]);
            acc1[i] = fmaf(a.y, v[i + 1], acc1[i]);
        }
        if (c + PF < CH) load_stage(s, c + PF);   // uniform branch
    }

    // combine the two C-halves through LDS: one barrier per kernel
    __shared__ float red[NS][128];
    if (half == 1) {
#pragma unroll
        for (int i = 0; i < NS; ++i) {
            red[i][2 * lane]     = acc0[i];
            red[i][2 * lane + 1] = acc1[i];
        }
    }
    __syncthreads();
    if (half == 0) {
        constexpr float scale = 1.0f / (float)C_;
        float* orow = out + (size_t)n * NS * HW + (size_t)h * W_ + w0;
#pragma unroll
        for (int i = 0; i < NS; ++i) {
            float2 o;
            o.x = (acc0[i] + red[i][2 * lane])     * scale;
            o.y = (acc1[i] + red[i][2 * lane + 1]) * scale;
            *(float2*)(orow + (size_t)i * HW) = o;
        }
    }
}

extern "C" void kernel_launch(void* const* d_in, const int* in_sizes, int n_in,
                              void* d_out, int out_size, void* d_ws, size_t ws_size,
                              hipStream_t stream) {
    const float* f1 = (const float*)d_in[0];
    const float* f2 = (const float*)d_in[1];
    float* out = (float*)d_out;
    cost_volume_kernel<<<dim3(TILES), dim3(128), 0, stream>>>(f1, f2, out);
}